// Round 6
// baseline (244.778 us; speedup 1.0000x reference)
//
#include <hip/hip_runtime.h>

#define N_NODES 100000
#define N_EDGES 1600000
#define F 16

// 512 edges per block: 4 waves x 4 iterations x 32 edges. 1.6M/512 = 3125 blocks.
#define EDGES_PER_BLOCK 512
#define ITERS 4

#define WS_ELEMS (N_NODES * F)           // 1.6M bf16 accumulators (3.2 MB in d_ws)
#define WS_UINT4 (WS_ELEMS / 8)          // 200000 uint4s
#define CVT_THREADS (WS_ELEMS / 8)       // 8 bf16 per thread

typedef __attribute__((ext_vector_type(8))) short bf16x8;  // 8 bf16 (4 VGPRs)
typedef __attribute__((ext_vector_type(4))) float f32x4;   // MFMA C/D

__global__ __launch_bounds__(256) void zero_ws_kernel(uint4* __restrict__ ws) {
    int i = blockIdx.x * 256 + threadIdx.x;
    if (i < WS_UINT4) ws[i] = make_uint4(0u, 0u, 0u, 0u);
}

// Expand bf16 accumulator -> f32 output (overwrites ALL of out; no out zeroing).
__global__ __launch_bounds__(256) void ws_to_out_kernel(const uint4* __restrict__ ws,
                                                        float4* __restrict__ out) {
    int i = blockIdx.x * 256 + threadIdx.x;
    if (i >= CVT_THREADS) return;
    const uint4 v = ws[i];
    float4 a, b;
    a.x = __builtin_bit_cast(float, v.x << 16);
    a.y = __builtin_bit_cast(float, v.x & 0xffff0000u);
    a.z = __builtin_bit_cast(float, v.y << 16);
    a.w = __builtin_bit_cast(float, v.y & 0xffff0000u);
    b.x = __builtin_bit_cast(float, v.z << 16);
    b.y = __builtin_bit_cast(float, v.z & 0xffff0000u);
    b.z = __builtin_bit_cast(float, v.w << 16);
    b.w = __builtin_bit_cast(float, v.w & 0xffff0000u);
    out[2 * i + 0] = a;
    out[2 * i + 1] = b;
}

// pack two f32 -> one dword of 2 bf16 (RNE), single instruction.
__device__ __forceinline__ unsigned pk_bf16(float lo, float hi) {
    unsigned r;
    asm("v_cvt_pk_bf16_f32 %0, %1, %2" : "=v"(r) : "v"(lo), "v"(hi));
    return r;
}

// Round-5 post-mortem: r3/r4/r5 all pin at 25.6M dword-atomics / ~89us ~= 1
// atomic per L2 channel per cycle (128 channels) -- a dword-atomic THROUGHPUT
// ceiling, insensitive to ILP/MLP. This version halves the atomic dword count:
//  (a) swap MFMA operands (D = W*X): A/B fragment layouts are symmetric for
//      16x16x32, so only the arg order changes; D rows become features ->
//      each lane holds 4 CONSECUTIVE features of one edge;
//  (b) global_atomic_pk_add_bf16 into a bf16 accumulator in d_ws: 8 dword
//      atomics per edge instead of 16 (12.8M total), then a convert kernel
//      expands ws -> f32 out.
__global__ __launch_bounds__(256, 4) void basis_conv_mfma(
    const float* __restrict__ x,          // [N_NODES, 16]
    const int*   __restrict__ edge_index, // [2, N_EDGES] (int32 on device)
    const float* __restrict__ edge_attr,  // [N_EDGES, 2]
    const float* __restrict__ weight,     // [4,4,16,16] = [cell][i][f]
    unsigned short* __restrict__ ws)      // [N_NODES, 16] bf16, pre-zeroed
{
    const int lane = threadIdx.x & 63;
    const int wid  = threadIdx.x >> 6;
    const int e15  = lane & 15;        // B col: edge within 16-edge unit
    const int fo   = lane & 15;        // A row: output feature (weight frag)
    const int c    = lane >> 4;        // K-chunk 0..3 within each MFMA
    const int hv   = c >> 1;           // 0: even cell of the pair, 1: odd cell
    const int i0   = (c & 1) * 8;      // input-feature offset within cell

    // --- A fragments (weights), loaded once. MFMA m covers cells 2m, 2m+1.
    // Lane element j: W^T[fo][K] with K = c*8 + j -> cell = 2m+hv, i = i0+j.
    bf16x8 bw[8];
#pragma unroll
    for (int m = 0; m < 8; ++m) {
        const float* wp = weight + (2 * m + hv) * 256 + i0 * 16 + fo;
        union { bf16x8 v; unsigned w[4]; } bb;
#pragma unroll
        for (int p = 0; p < 4; ++p)
            bb.w[p] = pk_bf16(wp[(2 * p) * 16], wp[(2 * p + 1) * 16]);
        bw[m] = bb.v;
    }

    const int wbase = blockIdx.x * EDGES_PER_BLOCK + wid * (32 * ITERS);

    // ---- pipeline state (col/attr 2-deep, x 1-deep, dst-row 0-deep) ----
    float2 at0[2], at1[2];
    int    col1[2];
    float4 xa0[2], xb0[2];
    {
#pragma unroll
        for (int u = 0; u < 2; ++u) {
            const int egA = wbase + u * 16;            // iter 0
            const int col0 = edge_index[N_EDGES + egA + e15];
            at0[u] = ((const float2*)edge_attr)[egA + e15];
            const float4* xv = (const float4*)(x + (size_t)col0 * 16 + i0);
            xa0[u] = xv[0]; xb0[u] = xv[1];
            const int egB = wbase + 32 + u * 16;       // iter 1 (< N_EDGES always)
            col1[u] = edge_index[N_EDGES + egB + e15];
            at1[u]  = ((const float2*)edge_attr)[egB + e15];
        }
    }

#pragma unroll 1
    for (int g = 0; g < ITERS; ++g) {
        // dst rows for CURRENT iter: issued first (oldest vmcnt), consumed
        // after the whole compute phase -> latency fully covered.
        int rowd[2];
#pragma unroll
        for (int u = 0; u < 2; ++u)
            rowd[u] = edge_index[wbase + g * 32 + u * 16 + e15];

        // x prefetch for iter g+1 (cols already resident)
        float4 xa1[2], xb1[2];
#pragma unroll
        for (int u = 0; u < 2; ++u) {
            const float4* xv = (const float4*)(x + (size_t)col1[u] * 16 + i0);
            xa1[u] = xv[0]; xb1[u] = xv[1];
        }

        // meta prefetch for iter g+2 (clamped; results unused on last iters)
        int col2[2]; float2 at2[2];
#pragma unroll
        for (int u = 0; u < 2; ++u) {
            int eg2 = wbase + (g + 2) * 32 + u * 16;
            eg2 = eg2 > (N_EDGES - 16) ? (N_EDGES - 16) : eg2;
            col2[u] = edge_index[N_EDGES + eg2 + e15];
            at2[u]  = ((const float2*)edge_attr)[eg2 + e15];
        }

        // ---- basis factors ----
        float bu_[2][4], bvE_[2], bvO_[2];
#pragma unroll
        for (int u = 0; u < 2; ++u) {
            float fu = (at0[u].x + 1.0f) * 1.5f;
            int iu = (int)fu; iu = iu < 0 ? 0 : (iu > 2 ? 2 : iu);
            const float wu1 = fu - (float)iu, wu0 = 1.0f - wu1;
            float fv = (at0[u].y + 1.0f) * 1.5f;
            int iv = (int)fv; iv = iv < 0 ? 0 : (iv > 2 ? 2 : iv);
            const float wv1 = fv - (float)iv, wv0 = 1.0f - wv1;

            bu_[u][0] = iu == 0 ? wu0 : 0.f;
            bu_[u][1] = iu == 0 ? wu1 : (iu == 1 ? wu0 : 0.f);
            bu_[u][2] = iu == 2 ? wu0 : (iu == 1 ? wu1 : 0.f);
            bu_[u][3] = iu == 2 ? wu1 : 0.f;
            const float bv0 = iv == 0 ? wv0 : 0.f;
            const float bv1 = iv == 0 ? wv1 : (iv == 1 ? wv0 : 0.f);
            const float bv2 = iv == 2 ? wv0 : (iv == 1 ? wv1 : 0.f);
            const float bv3 = iv == 2 ? wv1 : 0.f;
            bvE_[u] = hv ? bv1 : bv0;  // m even
            bvO_[u] = hv ? bv3 : bv2;  // m odd
        }

        // ---- 16 MFMAs, 4 independent chains; D = W(16f x 32K) * X(32K x 16e)
        f32x4 accE[2] = {{0.f,0.f,0.f,0.f},{0.f,0.f,0.f,0.f}};
        f32x4 accO[2] = {{0.f,0.f,0.f,0.f},{0.f,0.f,0.f,0.f}};
#pragma unroll
        for (int m = 0; m < 8; ++m) {
#pragma unroll
            for (int u = 0; u < 2; ++u) {
                const float t = bu_[u][m >> 1] * ((m & 1) ? bvO_[u] : bvE_[u]);
                union { bf16x8 v; unsigned w[4]; } aa;
                aa.w[0] = pk_bf16(t * xa0[u].x, t * xa0[u].y);
                aa.w[1] = pk_bf16(t * xa0[u].z, t * xa0[u].w);
                aa.w[2] = pk_bf16(t * xb0[u].x, t * xb0[u].y);
                aa.w[3] = pk_bf16(t * xb0[u].z, t * xb0[u].w);
                if (m & 1)
                    accO[u] = __builtin_amdgcn_mfma_f32_16x16x32_bf16(bw[m], aa.v, accO[u], 0, 0, 0);
                else
                    accE[u] = __builtin_amdgcn_mfma_f32_16x16x32_bf16(bw[m], aa.v, accE[u], 0, 0, 0);
            }
        }

        // D layout (swapped): lane holds features c*4+{0..3} of edge e15.
        // Two packed-bf16 atomics per lane cover the edge's 4 features.
#pragma unroll
        for (int u = 0; u < 2; ++u) {
            const f32x4 acc = accE[u] + accO[u];
            const unsigned d0 = pk_bf16(acc.x, acc.y);
            const unsigned d1 = pk_bf16(acc.z, acc.w);
            const unsigned long long a64 =
                (unsigned long long)ws + (size_t)rowd[u] * 32 + c * 8;
            asm volatile("global_atomic_pk_add_bf16 %0, %1, off"
                         :: "v"(a64), "v"(d0) : "memory");
            asm volatile("global_atomic_pk_add_bf16 %0, %1, off offset:4"
                         :: "v"(a64), "v"(d1) : "memory");
        }

        // ---- shift pipeline ----
#pragma unroll
        for (int u = 0; u < 2; ++u) {
            at0[u] = at1[u];
            xa0[u] = xa1[u]; xb0[u] = xb1[u];
            col1[u] = col2[u]; at1[u] = at2[u];
        }
    }
}

extern "C" void kernel_launch(void* const* d_in, const int* in_sizes, int n_in,
                              void* d_out, int out_size, void* d_ws, size_t ws_size,
                              hipStream_t stream) {
    const float* x  = (const float*)d_in[0];
    const int*   ei = (const int*)d_in[1];
    const float* ea = (const float*)d_in[2];
    const float* w  = (const float*)d_in[3];
    float* out = (float*)d_out;
    unsigned short* ws = (unsigned short*)d_ws;
    (void)out_size; (void)ws_size; (void)in_sizes; (void)n_in;

    zero_ws_kernel<<<(WS_UINT4 + 255) / 256, 256, 0, stream>>>((uint4*)ws);

    const int blocks = N_EDGES / EDGES_PER_BLOCK;  // 3125
    basis_conv_mfma<<<blocks, 256, 0, stream>>>(x, ei, ea, w, ws);

    ws_to_out_kernel<<<(CVT_THREADS + 255) / 256, 256, 0, stream>>>(
        (const uint4*)ws, (float4*)out);
}

// Round 8
// 226.540 us; speedup vs baseline: 1.0805x; 1.0805x over previous
//
#include <hip/hip_runtime.h>

#define N_NODES 100000
#define N_EDGES 1600000
#define F 16

// 512 edges per block: 4 waves x 4 iterations x 32 edges. 1.6M/512 = 3125 blocks.
#define EDGES_PER_BLOCK 512
#define ITERS 4

#define WS_U64   (N_NODES * 8)          // 800000 u64 accumulators (6.4 MB)
#define WS_UINT4 (WS_U64 / 2)           // 400000 uint4s to zero
#define FP_SCALE 262144.0f              // 2^18 fixed-point scale
#define FP_INV   (1.0f / 262144.0f)

typedef __attribute__((ext_vector_type(8))) short bf16x8;  // 8 bf16 (4 VGPRs)
typedef __attribute__((ext_vector_type(4))) float f32x4;   // MFMA C/D

__global__ __launch_bounds__(256) void zero_ws_kernel(uint4* __restrict__ ws) {
    int i = blockIdx.x * 256 + threadIdx.x;
    if (i < WS_UINT4) ws[i] = make_uint4(0u, 0u, 0u, 0u);
}

// Exact decode of the packed i64 fixed-point accumulators:
// T = (sum q_hi)<<32 + (sum q_lo); both lane-sums < 2^31 in magnitude, so
// lo = (int32)T recovers sum q_lo exactly and (T - lo)>>32 recovers sum q_hi.
__global__ __launch_bounds__(256) void ws_to_out_kernel(
    const unsigned long long* __restrict__ ws, float2* __restrict__ out) {
    int i = blockIdx.x * 256 + threadIdx.x;
    if (i >= WS_U64) return;
    const long long T = (long long)ws[i];
    const int lo = (int)(unsigned)(T & 0xffffffffULL);
    const int hi = (int)((T - (long long)lo) >> 32);
    out[i] = make_float2((float)lo * FP_INV, (float)hi * FP_INV);
}

// pack two f32 -> one dword of 2 bf16 (RNE), single instruction.
__device__ __forceinline__ unsigned pk_bf16(float lo, float hi) {
    unsigned r;
    asm("v_cvt_pk_bf16_f32 %0, %1, %2" : "=v"(r) : "v"(lo), "v"(hi));
    return r;
}

// r3-r5: pinned at 25.6M f32-dword atomics ~= 1 dword/channel/cycle (83us).
// r6: pk_add_bf16 is a 3.7x slow path. r7: no packed-f32 atomic exists.
// This round: halve atomic OPS with native 64-bit INT atomics — two features
// packed as i64 fixed point (scale 2^18; |q|<=1.05e6, sum over deg<=60 edges
// <= 6.3e7 << 2^31 -> no cross-lane carry, exact integer distributivity).
// 8 u64 atomics/edge (12.8M total) instead of 16 dword atomics (25.6M).
__global__ __launch_bounds__(256, 4) void basis_conv_mfma(
    const float* __restrict__ x,          // [N_NODES, 16]
    const int*   __restrict__ edge_index, // [2, N_EDGES] (int32 on device)
    const float* __restrict__ edge_attr,  // [N_EDGES, 2]
    const float* __restrict__ weight,     // [4,4,16,16] = [cell][i][f]
    unsigned long long* __restrict__ ws)  // [N_NODES, 8] i64 fx-pt, pre-zeroed
{
    const int lane = threadIdx.x & 63;
    const int wid  = threadIdx.x >> 6;
    const int e15  = lane & 15;        // B col: edge within 16-edge unit
    const int fo   = lane & 15;        // A row: output feature (weight frag)
    const int c    = lane >> 4;        // K-chunk 0..3 within each MFMA
    const int hv   = c >> 1;           // 0: even cell of the pair, 1: odd cell
    const int i0   = (c & 1) * 8;      // input-feature offset within cell

    // --- A fragments (weights), loaded once. MFMA m covers cells 2m, 2m+1.
    bf16x8 bw[8];
#pragma unroll
    for (int m = 0; m < 8; ++m) {
        const float* wp = weight + (2 * m + hv) * 256 + i0 * 16 + fo;
        union { bf16x8 v; unsigned w[4]; } bb;
#pragma unroll
        for (int p = 0; p < 4; ++p)
            bb.w[p] = pk_bf16(wp[(2 * p) * 16], wp[(2 * p + 1) * 16]);
        bw[m] = bb.v;
    }

    const int wbase = blockIdx.x * EDGES_PER_BLOCK + wid * (32 * ITERS);

    // ---- pipeline state (col/attr 2-deep, x 1-deep, dst-row 0-deep) ----
    float2 at0[2], at1[2];
    int    col1[2];
    float4 xa0[2], xb0[2];
    {
#pragma unroll
        for (int u = 0; u < 2; ++u) {
            const int egA = wbase + u * 16;            // iter 0
            const int col0 = edge_index[N_EDGES + egA + e15];
            at0[u] = ((const float2*)edge_attr)[egA + e15];
            const float4* xv = (const float4*)(x + (size_t)col0 * 16 + i0);
            xa0[u] = xv[0]; xb0[u] = xv[1];
            const int egB = wbase + 32 + u * 16;       // iter 1 (< N_EDGES always)
            col1[u] = edge_index[N_EDGES + egB + e15];
            at1[u]  = ((const float2*)edge_attr)[egB + e15];
        }
    }

#pragma unroll 1
    for (int g = 0; g < ITERS; ++g) {
        // dst rows for CURRENT iter: issued first (oldest vmcnt), consumed
        // after the whole compute phase -> latency fully covered.
        int rowd[2];
#pragma unroll
        for (int u = 0; u < 2; ++u)
            rowd[u] = edge_index[wbase + g * 32 + u * 16 + e15];

        // x prefetch for iter g+1 (cols already resident)
        float4 xa1[2], xb1[2];
#pragma unroll
        for (int u = 0; u < 2; ++u) {
            const float4* xv = (const float4*)(x + (size_t)col1[u] * 16 + i0);
            xa1[u] = xv[0]; xb1[u] = xv[1];
        }

        // meta prefetch for iter g+2 (clamped; results unused on last iters)
        int col2[2]; float2 at2[2];
#pragma unroll
        for (int u = 0; u < 2; ++u) {
            int eg2 = wbase + (g + 2) * 32 + u * 16;
            eg2 = eg2 > (N_EDGES - 16) ? (N_EDGES - 16) : eg2;
            col2[u] = edge_index[N_EDGES + eg2 + e15];
            at2[u]  = ((const float2*)edge_attr)[eg2 + e15];
        }

        // ---- basis factors ----
        float bu_[2][4], bvE_[2], bvO_[2];
#pragma unroll
        for (int u = 0; u < 2; ++u) {
            float fu = (at0[u].x + 1.0f) * 1.5f;
            int iu = (int)fu; iu = iu < 0 ? 0 : (iu > 2 ? 2 : iu);
            const float wu1 = fu - (float)iu, wu0 = 1.0f - wu1;
            float fv = (at0[u].y + 1.0f) * 1.5f;
            int iv = (int)fv; iv = iv < 0 ? 0 : (iv > 2 ? 2 : iv);
            const float wv1 = fv - (float)iv, wv0 = 1.0f - wv1;

            bu_[u][0] = iu == 0 ? wu0 : 0.f;
            bu_[u][1] = iu == 0 ? wu1 : (iu == 1 ? wu0 : 0.f);
            bu_[u][2] = iu == 2 ? wu0 : (iu == 1 ? wu1 : 0.f);
            bu_[u][3] = iu == 2 ? wu1 : 0.f;
            const float bv0 = iv == 0 ? wv0 : 0.f;
            const float bv1 = iv == 0 ? wv1 : (iv == 1 ? wv0 : 0.f);
            const float bv2 = iv == 2 ? wv0 : (iv == 1 ? wv1 : 0.f);
            const float bv3 = iv == 2 ? wv1 : 0.f;
            bvE_[u] = hv ? bv1 : bv0;  // m even
            bvO_[u] = hv ? bv3 : bv2;  // m odd
        }

        // ---- 16 MFMAs, 4 independent chains; D = W(16f x 32K) * X(32K x 16e)
        f32x4 accE[2] = {{0.f,0.f,0.f,0.f},{0.f,0.f,0.f,0.f}};
        f32x4 accO[2] = {{0.f,0.f,0.f,0.f},{0.f,0.f,0.f,0.f}};
#pragma unroll
        for (int m = 0; m < 8; ++m) {
#pragma unroll
            for (int u = 0; u < 2; ++u) {
                const float t = bu_[u][m >> 1] * ((m & 1) ? bvO_[u] : bvE_[u]);
                union { bf16x8 v; unsigned w[4]; } aa;
                aa.w[0] = pk_bf16(t * xa0[u].x, t * xa0[u].y);
                aa.w[1] = pk_bf16(t * xa0[u].z, t * xa0[u].w);
                aa.w[2] = pk_bf16(t * xb0[u].x, t * xb0[u].y);
                aa.w[3] = pk_bf16(t * xb0[u].z, t * xb0[u].w);
                if (m & 1)
                    accO[u] = __builtin_amdgcn_mfma_f32_16x16x32_bf16(bw[m], aa.v, accO[u], 0, 0, 0);
                else
                    accE[u] = __builtin_amdgcn_mfma_f32_16x16x32_bf16(bw[m], aa.v, accE[u], 0, 0, 0);
            }
        }

        // D layout (swapped, r6-verified): lane holds features c*4+{0..3} of
        // edge e15. Pack feature pairs as i64 fixed point; 2 u64 atomics/lane.
#pragma unroll
        for (int u = 0; u < 2; ++u) {
            const f32x4 acc = accE[u] + accO[u];
            const long long q0 = (long long)(int)(acc.x * FP_SCALE)
                               + ((long long)(int)(acc.y * FP_SCALE) << 32);
            const long long q1 = (long long)(int)(acc.z * FP_SCALE)
                               + ((long long)(int)(acc.w * FP_SCALE) << 32);
            unsigned long long* p = ws + (size_t)rowd[u] * 8 + c * 2;
            atomicAdd(p,     (unsigned long long)q0);
            atomicAdd(p + 1, (unsigned long long)q1);
        }

        // ---- shift pipeline ----
#pragma unroll
        for (int u = 0; u < 2; ++u) {
            at0[u] = at1[u];
            xa0[u] = xa1[u]; xb0[u] = xb1[u];
            col1[u] = col2[u]; at1[u] = at2[u];
        }
    }
}

extern "C" void kernel_launch(void* const* d_in, const int* in_sizes, int n_in,
                              void* d_out, int out_size, void* d_ws, size_t ws_size,
                              hipStream_t stream) {
    const float* x  = (const float*)d_in[0];
    const int*   ei = (const int*)d_in[1];
    const float* ea = (const float*)d_in[2];
    const float* w  = (const float*)d_in[3];
    float* out = (float*)d_out;
    unsigned long long* ws = (unsigned long long*)d_ws;
    (void)out_size; (void)ws_size; (void)in_sizes; (void)n_in;

    zero_ws_kernel<<<(WS_UINT4 + 255) / 256, 256, 0, stream>>>((uint4*)ws);

    const int blocks = N_EDGES / EDGES_PER_BLOCK;  // 3125
    basis_conv_mfma<<<blocks, 256, 0, stream>>>(x, ei, ea, w, ws);

    ws_to_out_kernel<<<(WS_U64 + 255) / 256, 256, 0, stream>>>(ws, (float2*)out);
}